// Round 1
// baseline (740.651 us; speedup 1.0000x reference)
//
#include <hip/hip_runtime.h>
#include <math.h>

// Problem: J=25, F=38400, C=128, B=128 (dims derived from in_sizes at launch).
// x is (J,F,C) fp32; idx sorted; out (J,B,C) fp32.
// Two structural HBM passes over x (491 MB > 256 MB L3) -> floor ~156 us.

__global__ void seg_bounds_kernel(const int* __restrict__ idx, int F, int B,
                                  int* __restrict__ seg) {
    int b = blockIdx.x * blockDim.x + threadIdx.x;
    if (b > B) return;
    // first f with idx[f] >= b  (idx sorted ascending)
    int lo = 0, hi = F;
    while (lo < hi) {
        int mid = (lo + hi) >> 1;
        if (idx[mid] < b) lo = mid + 1; else hi = mid;
    }
    seg[b] = lo;
}

// One block per (j,b). 256 threads = 8 frame-rows x 32 lanes, float4/lane
// (C==128). Coalesced 16B/lane streaming loads, register accumulation,
// LDS tree-reduce over the 8 rows, divide by count.
__global__ void __launch_bounds__(256) seg_mean_kernel(
    const float* __restrict__ x, const int* __restrict__ seg,
    int F, int B, int C, float* __restrict__ mean) {
    const int bid = blockIdx.x;
    const int j = bid / B, b = bid - j * B;
    const int f0 = seg[b], f1 = seg[b + 1];
    const int tid = threadIdx.x;
    const int lane32 = tid & 31;   // channel slice: c = lane32*4 .. +3
    const int row = tid >> 5;      // frame-row 0..7

    const float4* __restrict__ xp = (const float4*)(x + (size_t)j * F * C);
    float4 acc = make_float4(0.f, 0.f, 0.f, 0.f);
    for (int f = f0 + row; f < f1; f += 8) {
        float4 v = xp[(size_t)f * 32 + lane32];
        acc.x += v.x; acc.y += v.y; acc.z += v.z; acc.w += v.w;
    }

    __shared__ float4 s[256];
    s[tid] = acc;
    __syncthreads();
#pragma unroll
    for (int stride = 128; stride >= 32; stride >>= 1) {
        if (tid < stride) {
            float4 o = s[tid + stride], m = s[tid];
            m.x += o.x; m.y += o.y; m.z += o.z; m.w += o.w;
            s[tid] = m;
        }
        __syncthreads();
    }
    if (tid < 32) {
        float inv = 1.0f / fmaxf((float)(f1 - f0), 1.0f);
        float4 m = s[tid];
        float4 r = make_float4(m.x * inv, m.y * inv, m.z * inv, m.w * inv);
        ((float4*)(mean + ((size_t)j * B + b) * C))[tid] = r;
    }
}

// One block (C=128 threads) per output row: gc[r,t] = tanh(sum_k mean[r,k]*W[k,t]).
// W (64 KB) stays L2-resident; per-k reads are coalesced across t.
__global__ void gc_kernel(const float* __restrict__ mean,
                          const float* __restrict__ W,
                          int C, float* __restrict__ gc) {
    const int r = blockIdx.x;
    const int t = threadIdx.x;
    __shared__ float srow[128];
    srow[t] = mean[(size_t)r * C + t];
    __syncthreads();
    float acc = 0.f;
#pragma unroll 8
    for (int k = 0; k < 128; ++k) acc = fmaf(srow[k], W[k * C + t], acc);
    gc[(size_t)r * C + t] = tanhf(acc);
}

// One block per (j,b). Per frame-row: partial dot(x4, gc4), 5-step shuffle
// reduce within the 32-lane group (xor masks <=16 never cross the group, and
// all 32 lanes of a group share f so they exit the loop together), sigmoid,
// accumulate gate*x. Then LDS reduce + scale + store.
__global__ void __launch_bounds__(256) gate_scatter_kernel(
    const float* __restrict__ x, const float* __restrict__ gc,
    const int* __restrict__ seg, int F, int B, int C,
    float* __restrict__ out) {
    const int bid = blockIdx.x;
    const int j = bid / B, b = bid - j * B;
    const int f0 = seg[b], f1 = seg[b + 1];
    const int tid = threadIdx.x;
    const int lane32 = tid & 31;
    const int row = tid >> 5;

    const float4* __restrict__ xp = (const float4*)(x + (size_t)j * F * C);
    const float4 g = ((const float4*)(gc + ((size_t)j * B + b) * C))[lane32];

    float4 acc = make_float4(0.f, 0.f, 0.f, 0.f);
    for (int f = f0 + row; f < f1; f += 8) {
        float4 v = xp[(size_t)f * 32 + lane32];
        float p = v.x * g.x + v.y * g.y + v.z * g.z + v.w * g.w;
#pragma unroll
        for (int m = 16; m >= 1; m >>= 1) p += __shfl_xor(p, m, 64);
        float gate = 1.0f / (1.0f + __expf(-p));
        acc.x += gate * v.x; acc.y += gate * v.y;
        acc.z += gate * v.z; acc.w += gate * v.w;
    }

    __shared__ float4 s[256];
    s[tid] = acc;
    __syncthreads();
#pragma unroll
    for (int stride = 128; stride >= 32; stride >>= 1) {
        if (tid < stride) {
            float4 o = s[tid + stride], m = s[tid];
            m.x += o.x; m.y += o.y; m.z += o.z; m.w += o.w;
            s[tid] = m;
        }
        __syncthreads();
    }
    if (tid < 32) {
        float inv = 1.0f / fmaxf((float)(f1 - f0), 1.0f);
        float4 m = s[tid];
        float4 r = make_float4(m.x * inv, m.y * inv, m.z * inv, m.w * inv);
        ((float4*)(out + ((size_t)j * B + b) * C))[tid] = r;
    }
}

extern "C" void kernel_launch(void* const* d_in, const int* in_sizes, int n_in,
                              void* d_out, int out_size, void* d_ws, size_t ws_size,
                              hipStream_t stream) {
    const float* x  = (const float*)d_in[0];
    const int* idx  = (const int*)d_in[1];
    const float* W  = (const float*)d_in[3];
    float* out      = (float*)d_out;

    const int F = in_sizes[1];
    int C = 1;
    while ((long long)C * C < (long long)in_sizes[3]) ++C;   // C = sqrt(|W|) = 128
    const int J = in_sizes[0] / (F * C);                     // 25
    const int B = out_size / (J * C);                        // 128

    char* ws = (char*)d_ws;
    int* seg = (int*)ws;
    size_t off = (((size_t)(B + 1) * sizeof(int)) + 255) & ~(size_t)255;
    float* mean = (float*)(ws + off);
    off += (((size_t)J * B * C * sizeof(float)) + 255) & ~(size_t)255;
    float* gcb = (float*)(ws + off);

    seg_bounds_kernel<<<(B + 1 + 255) / 256, 256, 0, stream>>>(idx, F, B, seg);
    seg_mean_kernel<<<J * B, 256, 0, stream>>>(x, seg, F, B, C, mean);
    gc_kernel<<<J * B, C, 0, stream>>>(mean, W, C, gcb);
    gate_scatter_kernel<<<J * B, 256, 0, stream>>>(x, gcb, seg, F, B, C, out);
}

// Round 2
// 735.273 us; speedup vs baseline: 1.0073x; 1.0073x over previous
//
#include <hip/hip_runtime.h>
#include <math.h>

// Problem: J=25, F=38400, C=128, B=128 (dims derived at launch).
// x (J,F,C) fp32; idx sorted; out (J,B,C) fp32.
// Two structural HBM passes over x (491 MB > 256 MB L3) -> floor ~156 us.
// R2: unroll x4 in both streaming kernels -> 4 outstanding loads/wave,
// 4 independent shuffle-reduce chains in gate_scatter.

__global__ void seg_bounds_kernel(const int* __restrict__ idx, int F, int B,
                                  int* __restrict__ seg) {
    int b = blockIdx.x * blockDim.x + threadIdx.x;
    if (b > B) return;
    int lo = 0, hi = F;
    while (lo < hi) {
        int mid = (lo + hi) >> 1;
        if (idx[mid] < b) lo = mid + 1; else hi = mid;
    }
    seg[b] = lo;
}

__device__ __forceinline__ void f4add(float4& a, const float4& v) {
    a.x += v.x; a.y += v.y; a.z += v.z; a.w += v.w;
}

// One block per (j,b). 256 threads = 8 frame-rows x 32 lanes, float4/lane.
// Unrolled x4: frames f, f+8, f+16, f+24 per iteration.
__global__ void __launch_bounds__(256) seg_mean_kernel(
    const float* __restrict__ x, const int* __restrict__ seg,
    int F, int B, float* __restrict__ mean) {
    const int bid = blockIdx.x;
    const int j = bid / B, b = bid - j * B;
    const int f0 = seg[b], f1 = seg[b + 1];
    const int tid = threadIdx.x;
    const int lane32 = tid & 31;
    const int row = tid >> 5;

    const float4* __restrict__ xp =
        (const float4*)(x + (size_t)j * F * 128) + lane32;
    float4 a0 = make_float4(0.f, 0.f, 0.f, 0.f);
    float4 a1 = make_float4(0.f, 0.f, 0.f, 0.f);

    int f = f0 + row;
    const float4* p = xp + (size_t)f * 32;
    for (; f + 24 < f1; f += 32, p += 1024) {
        float4 v0 = p[0];
        float4 v1 = p[256];
        float4 v2 = p[512];
        float4 v3 = p[768];
        f4add(a0, v0); f4add(a1, v1); f4add(a0, v2); f4add(a1, v3);
    }
    for (; f < f1; f += 8, p += 256) f4add(a0, p[0]);
    f4add(a0, a1);

    __shared__ float4 s[256];
    s[tid] = a0;
    __syncthreads();
#pragma unroll
    for (int stride = 128; stride >= 32; stride >>= 1) {
        if (tid < stride) {
            float4 o = s[tid + stride], m = s[tid];
            m.x += o.x; m.y += o.y; m.z += o.z; m.w += o.w;
            s[tid] = m;
        }
        __syncthreads();
    }
    if (tid < 32) {
        float inv = 1.0f / fmaxf((float)(f1 - f0), 1.0f);
        float4 m = s[tid];
        ((float4*)(mean + ((size_t)j * B + b) * 128))[tid] =
            make_float4(m.x * inv, m.y * inv, m.z * inv, m.w * inv);
    }
}

// gc[r,t] = tanh(sum_k mean[r,k] * W[k,t]); W stays L2-resident.
__global__ void gc_kernel(const float* __restrict__ mean,
                          const float* __restrict__ W,
                          float* __restrict__ gc) {
    const int r = blockIdx.x;
    const int t = threadIdx.x;
    __shared__ float srow[128];
    srow[t] = mean[(size_t)r * 128 + t];
    __syncthreads();
    float acc = 0.f;
#pragma unroll 8
    for (int k = 0; k < 128; ++k) acc = fmaf(srow[k], W[k * 128 + t], acc);
    gc[(size_t)r * 128 + t] = tanhf(acc);
}

__device__ __forceinline__ float dot4(const float4& a, const float4& b) {
    return a.x * b.x + a.y * b.y + a.z * b.z + a.w * b.w;
}

// One block per (j,b). Unrolled x4: 4 independent shuffle-reduce chains.
// xor masks <=16 stay within each 32-lane half of the wave; both rows of a
// wave exit the loop together (shared f), so no divergent-shuffle hazard.
__global__ void __launch_bounds__(256) gate_scatter_kernel(
    const float* __restrict__ x, const float* __restrict__ gc,
    const int* __restrict__ seg, int F, int B,
    float* __restrict__ out) {
    const int bid = blockIdx.x;
    const int j = bid / B, b = bid - j * B;
    const int f0 = seg[b], f1 = seg[b + 1];
    const int tid = threadIdx.x;
    const int lane32 = tid & 31;
    const int row = tid >> 5;

    const float4* __restrict__ xp =
        (const float4*)(x + (size_t)j * F * 128) + lane32;
    const float4 g = ((const float4*)(gc + ((size_t)j * B + b) * 128))[lane32];

    float4 a0 = make_float4(0.f, 0.f, 0.f, 0.f);
    float4 a1 = make_float4(0.f, 0.f, 0.f, 0.f);

    int f = f0 + row;
    const float4* p = xp + (size_t)f * 32;
    for (; f + 24 < f1; f += 32, p += 1024) {
        float4 v0 = p[0];
        float4 v1 = p[256];
        float4 v2 = p[512];
        float4 v3 = p[768];
        float p0 = dot4(v0, g), p1 = dot4(v1, g),
              p2 = dot4(v2, g), p3 = dot4(v3, g);
#pragma unroll
        for (int m = 16; m >= 1; m >>= 1) {
            p0 += __shfl_xor(p0, m, 64);
            p1 += __shfl_xor(p1, m, 64);
            p2 += __shfl_xor(p2, m, 64);
            p3 += __shfl_xor(p3, m, 64);
        }
        float g0 = 1.0f / (1.0f + __expf(-p0));
        float g1 = 1.0f / (1.0f + __expf(-p1));
        float g2 = 1.0f / (1.0f + __expf(-p2));
        float g3 = 1.0f / (1.0f + __expf(-p3));
        a0.x += g0 * v0.x + g2 * v2.x; a0.y += g0 * v0.y + g2 * v2.y;
        a0.z += g0 * v0.z + g2 * v2.z; a0.w += g0 * v0.w + g2 * v2.w;
        a1.x += g1 * v1.x + g3 * v3.x; a1.y += g1 * v1.y + g3 * v3.y;
        a1.z += g1 * v1.z + g3 * v3.z; a1.w += g1 * v1.w + g3 * v3.w;
    }
    for (; f < f1; f += 8, p += 256) {
        float4 v = p[0];
        float pp = dot4(v, g);
#pragma unroll
        for (int m = 16; m >= 1; m >>= 1) pp += __shfl_xor(pp, m, 64);
        float gg = 1.0f / (1.0f + __expf(-pp));
        a0.x += gg * v.x; a0.y += gg * v.y; a0.z += gg * v.z; a0.w += gg * v.w;
    }
    f4add(a0, a1);

    __shared__ float4 s[256];
    s[tid] = a0;
    __syncthreads();
#pragma unroll
    for (int stride = 128; stride >= 32; stride >>= 1) {
        if (tid < stride) {
            float4 o = s[tid + stride], m = s[tid];
            m.x += o.x; m.y += o.y; m.z += o.z; m.w += o.w;
            s[tid] = m;
        }
        __syncthreads();
    }
    if (tid < 32) {
        float inv = 1.0f / fmaxf((float)(f1 - f0), 1.0f);
        float4 m = s[tid];
        ((float4*)(out + ((size_t)j * B + b) * 128))[tid] =
            make_float4(m.x * inv, m.y * inv, m.z * inv, m.w * inv);
    }
}

extern "C" void kernel_launch(void* const* d_in, const int* in_sizes, int n_in,
                              void* d_out, int out_size, void* d_ws, size_t ws_size,
                              hipStream_t stream) {
    const float* x  = (const float*)d_in[0];
    const int* idx  = (const int*)d_in[1];
    const float* W  = (const float*)d_in[3];
    float* out      = (float*)d_out;

    const int F = in_sizes[1];
    int C = 1;
    while ((long long)C * C < (long long)in_sizes[3]) ++C;   // 128
    const int J = in_sizes[0] / (F * C);                     // 25
    const int B = out_size / (J * C);                        // 128

    char* ws = (char*)d_ws;
    int* seg = (int*)ws;
    size_t off = (((size_t)(B + 1) * sizeof(int)) + 255) & ~(size_t)255;
    float* mean = (float*)(ws + off);
    off += (((size_t)J * B * C * sizeof(float)) + 255) & ~(size_t)255;
    float* gcb = (float*)(ws + off);

    seg_bounds_kernel<<<(B + 1 + 255) / 256, 256, 0, stream>>>(idx, F, B, seg);
    seg_mean_kernel<<<J * B, 256, 0, stream>>>(x, seg, F, B, mean);
    gc_kernel<<<J * B, C, 0, stream>>>(mean, W, gcb);
    gate_scatter_kernel<<<J * B, 256, 0, stream>>>(x, gcb, seg, F, B, out);
}